// Round 6
// baseline (1532.978 us; speedup 1.0000x reference)
//
#include <hip/hip_runtime.h>
#include <cstdint>
#include <cstddef>

// Problem constants (match reference setup_inputs)
#define Bb   256
#define Tt   250
#define DIN  700
#define Hh   128
#define DOUT 20

// ---------------------------------------------------------------------------
// Phase 1: H1[b*T+t][h] = x[b][t][:] @ W1[:,h] + b1[h]
// M=64000, K=700, N=128. 128x128 tile, BK=20, 256 threads, 8x8 micro-tile.
// R6: register-staged DOUBLE-BUFFERED LDS, ONE barrier per k-iter. Global
// loads for tile k+1 issue at iter top; their vmcnt wait lands at the
// reg->LDS[alt] writes AFTER the 1280 FMAs are issued -> latency covered.
// B column groups XOR-swizzled (R3): compute-loop B reads are 2-way (free).
// ---------------------------------------------------------------------------
constexpr int BM  = 128;
constexpr int BK  = 20;
constexpr int BN  = 128;
constexpr int BMP = BM + 4;   // padded row length for Ast (staging writes)

__device__ __forceinline__ int bswz(int g) { return g ^ (g >> 3); }

__global__ __launch_bounds__(256, 2) void gemm_h1(const float* __restrict__ x,
                                                  const float* __restrict__ W1,
                                                  const float* __restrict__ b1,
                                                  float* __restrict__ H1) {
    __shared__ float Ast[2][BK][BMP];  // x tile, TRANSPOSED: Ast[.][k][m]
    __shared__ float Bs [2][BK][BN];   // W1 tile, column-group swizzled

    const int tid = threadIdx.x;
    const int tx  = tid & 15;       // col group: cols tx*8 .. +7
    const int ty  = tid >> 4;       // row group: rows ty*8 .. +7
    const int m0  = blockIdx.x * BM;

    const int c0 = bswz(tx * 2) * 4;
    const int c1 = bswz(tx * 2 + 1) * 4;

    float acc[8][8];
#pragma unroll
    for (int r = 0; r < 8; ++r)
#pragma unroll
        for (int c = 0; c < 8; ++c) acc[r][c] = 0.f;

    float4 ra[3], rb[3];   // register staging (idx = tid + u*256 < 640)

    auto load_tile = [&](int k0) {
#pragma unroll
        for (int u = 0; u < 3; ++u) {
            const int idx = tid + u * 256;
            if (idx < 640) {
                const int row = idx / 5;
                const int kq  = (idx - row * 5) * 4;
                ra[u] = *(const float4*)&x[(size_t)(m0 + row) * DIN + k0 + kq];
                const int kr = idx >> 5;
                const int g  = idx & 31;
                rb[u] = *(const float4*)&W1[(size_t)(k0 + kr) * BN + g * 4];
            }
        }
    };
    auto store_tile = [&](int bufi) {
#pragma unroll
        for (int u = 0; u < 3; ++u) {
            const int idx = tid + u * 256;
            if (idx < 640) {
                const int row = idx / 5;
                const int kq  = (idx - row * 5) * 4;
                Ast[bufi][kq + 0][row] = ra[u].x;
                Ast[bufi][kq + 1][row] = ra[u].y;
                Ast[bufi][kq + 2][row] = ra[u].z;
                Ast[bufi][kq + 3][row] = ra[u].w;
                const int kr = idx >> 5;
                const int g  = idx & 31;
                *(float4*)&Bs[bufi][kr][bswz(g) * 4] = rb[u];
            }
        }
    };

    load_tile(0);
    store_tile(0);
    __syncthreads();

    int buf = 0;
    for (int it = 0; it < 35; ++it) {
        if (it < 34) load_tile((it + 1) * BK);   // in flight during compute

#pragma unroll
        for (int kk = 0; kk < BK; ++kk) {
            float a[8], bv[8];
            *(float4*)&a[0]  = *(const float4*)&Ast[buf][kk][ty * 8];
            *(float4*)&a[4]  = *(const float4*)&Ast[buf][kk][ty * 8 + 4];
            *(float4*)&bv[0] = *(const float4*)&Bs[buf][kk][c0];
            *(float4*)&bv[4] = *(const float4*)&Bs[buf][kk][c1];
#pragma unroll
            for (int r = 0; r < 8; ++r)
#pragma unroll
                for (int c = 0; c < 8; ++c)
                    acc[r][c] = fmaf(a[r], bv[c], acc[r][c]);
        }

        if (it < 34) {
            store_tile(buf ^ 1);   // vmcnt wait lands here, post-compute
            __syncthreads();       // the ONLY barrier per iter
            buf ^= 1;
        }
    }

    float bb[8];
#pragma unroll
    for (int c = 0; c < 8; ++c) bb[c] = b1[tx * 8 + c];

#pragma unroll
    for (int r = 0; r < 8; ++r) {
        size_t row = (size_t)(m0 + ty * 8 + r);
        float4 o0, o1;
        o0.x = acc[r][0] + bb[0]; o0.y = acc[r][1] + bb[1];
        o0.z = acc[r][2] + bb[2]; o0.w = acc[r][3] + bb[3];
        o1.x = acc[r][4] + bb[4]; o1.y = acc[r][5] + bb[5];
        o1.z = acc[r][6] + bb[6]; o1.w = acc[r][7] + bb[7];
        *(float4*)&H1[row * Hh + tx * 8]     = o0;
        *(float4*)&H1[row * Hh + tx * 8 + 4] = o1;
    }
}

// ---------------------------------------------------------------------------
// Phase 2: recurrence, wave-autonomous, critical path fully on-chip.
// 256 blocks; 256 threads stage this batch row's ENTIRE h1 (250x128 f32 =
// 125 KB, proven-launchable per R4's 131584 B) into LDS in one coalesced
// burst, then threads >= 64 exit and wave 0 runs the 250-step chain with
// ZERO global loads on the critical path (h1 via ds_read, prefetched one
// step ahead; ~120cyc LDS latency covered by the step body). Spike gathers
// (rare, P~15%/step) go straight to L2-hot global weights. Readout via
// shuffles (no barrier after the other waves exit). Ascending-k gather
// order keeps summation == dense reference order.
// ---------------------------------------------------------------------------
__global__ __launch_bounds__(256) void recurrent(
    const float* __restrict__ H1,   const float* __restrict__ rcW1,
    const float* __restrict__ rcb1, const float* __restrict__ W2,
    const float* __restrict__ b2,   const float* __restrict__ rcW2,
    const float* __restrict__ rcb2, const float* __restrict__ W3,
    const float* __restrict__ b3,   float* __restrict__ out) {

    __shared__ float sH1[Tt * Hh];   // 128000 B

    const int tid = threadIdx.x;
    const int b   = blockIdx.x;
    const float* __restrict__ h1p = H1 + (size_t)b * Tt * Hh;

    // ---- stage h1 row: 8000 float4, coalesced across 256 threads ----
    for (int i = tid * 4; i < Tt * Hh; i += 256 * 4)
        *(float4*)&sH1[i] = *(const float4*)&h1p[i];
    __syncthreads();

    if (tid >= 64) return;           // wave 0 carries the chain
    const int lane = tid;

    const float rcb1x = rcb1[lane], rcb1y = rcb1[lane + 64];
    const float bb2x  = b2[lane]      + rcb2[lane];
    const float bb2y  = b2[lane + 64] + rcb2[lane + 64];

    float v1x = 0.f, v1y = 0.f, v2x = 0.f, v2y = 0.f;
    float cntx = 0.f, cnty = 0.f;
    float u1gx = 0.f, u1gy = 0.f;    // rcW1 gather result (prev step)
    float u2gx = 0.f, u2gy = 0.f;    // rcW2 gather result (prev step)

    float h1x = sH1[lane], h1y = sH1[lane + 64];

    for (int t = 0; t < Tt; ++t) {
        // ---- LIF 1 (consume current, prefetch next from LDS) ----
        const float u1xv = h1x + rcb1x + u1gx;
        const float u1yv = h1y + rcb1y + u1gy;
        const int tn  = (t + 1 < Tt) ? (t + 1) : t;
        const int off = tn * Hh + lane;
        const float h1xn = sH1[off];
        const float h1yn = sH1[off + 64];
        v1x = v1x + (u1xv - v1x) * 0.5f;
        v1y = v1y + (u1yv - v1y) * 0.5f;
        const bool s1x = (v1x >= 1.0f);
        const bool s1y = (v1y >= 1.0f);
        if (s1x) v1x = 0.f;
        if (s1y) v1y = 0.f;
        const unsigned long long a0 = __ballot((int)s1x);
        const unsigned long long a1 = __ballot((int)s1y);

        // ---- layer-1 spike fanout: W2 (this step) + rcW1 (next) ----
        float uW2x = 0.f, uW2y = 0.f, g1x = 0.f, g1y = 0.f;
        if (a0 | a1) {
            unsigned long long m = a0;
            int base = 0;
            for (int hlf = 0; hlf < 2; ++hlf) {
                while (m) {
                    const int k = (int)__ffsll(m) - 1 + base;
                    m &= (m - 1ull);
                    const float* __restrict__ pw = W2 + k * Hh;
                    const float* __restrict__ pr = rcW1 + k * Hh;
                    uW2x += pw[lane]; uW2y += pw[lane + 64];
                    g1x  += pr[lane]; g1y  += pr[lane + 64];
                }
                m = a1; base = 64;
            }
        }
        u1gx = g1x; u1gy = g1y;

        // ---- LIF 2 ----
        const float u2xv = bb2x + uW2x + u2gx;
        const float u2yv = bb2y + uW2y + u2gy;
        v2x = v2x + (u2xv - v2x) * 0.5f;
        v2y = v2y + (u2yv - v2y) * 0.5f;
        const bool s2x = (v2x >= 1.0f);
        const bool s2y = (v2y >= 1.0f);
        if (s2x) v2x = 0.f;
        if (s2y) v2y = 0.f;
        cntx += s2x ? 1.f : 0.f;
        cnty += s2y ? 1.f : 0.f;
        const unsigned long long c0m = __ballot((int)s2x);
        const unsigned long long c1m = __ballot((int)s2y);

        float g2x = 0.f, g2y = 0.f;
        if (c0m | c1m) {
            unsigned long long m = c0m;
            int base = 0;
            for (int hlf = 0; hlf < 2; ++hlf) {
                while (m) {
                    const int k = (int)__ffsll(m) - 1 + base;
                    m &= (m - 1ull);
                    const float* __restrict__ pr = rcW2 + k * Hh;
                    g2x += pr[lane]; g2y += pr[lane + 64];
                }
                m = c1m; base = 64;
            }
        }
        u2gx = g2x; u2gy = g2y;

        h1x = h1xn; h1y = h1yn;
    }

    // ---- readout via shuffles: out[b] = cnt2 @ W3 + T*b3 ----
    float o = (lane < DOUT) ? (float)Tt * b3[lane] : 0.f;
    for (int k = 0; k < 64; ++k) {
        const float c = __shfl(cntx, k);
        if (lane < DOUT) o = fmaf(c, W3[k * DOUT + lane], o);
    }
    for (int k = 0; k < 64; ++k) {
        const float c = __shfl(cnty, k);
        if (lane < DOUT) o = fmaf(c, W3[(k + 64) * DOUT + lane], o);
    }
    if (lane < DOUT) out[b * DOUT + lane] = o;
}

// ---------------------------------------------------------------------------
extern "C" void kernel_launch(void* const* d_in, const int* in_sizes, int n_in,
                              void* d_out, int out_size, void* d_ws, size_t ws_size,
                              hipStream_t stream) {
    const float* x    = (const float*)d_in[0];
    const float* W1   = (const float*)d_in[1];
    const float* b1   = (const float*)d_in[2];
    const float* rcW1 = (const float*)d_in[3];
    const float* rcb1 = (const float*)d_in[4];
    const float* W2   = (const float*)d_in[5];
    const float* b2   = (const float*)d_in[6];
    const float* rcW2 = (const float*)d_in[7];
    const float* rcb2 = (const float*)d_in[8];
    const float* W3   = (const float*)d_in[9];
    const float* b3   = (const float*)d_in[10];

    float* out = (float*)d_out;
    float* H1  = (float*)d_ws;   // 64000 x 128 f32 = 32.77 MB

    gemm_h1<<<(Bb * Tt) / BM, 256, 0, stream>>>(x, W1, b1, H1);
    recurrent<<<Bb, 256, 0, stream>>>(H1, rcW1, rcb1, W2, b2, rcW2, rcb2, W3,
                                      b3, out);
}